// Round 9
// baseline (612.582 us; speedup 1.0000x reference)
//
#include <hip/hip_runtime.h>
#include <math.h>

// MoE gate: bf16x3 split MFMA GEMM, fully register-resident K-loop (no LDS,
// no barriers: per-wave B/A direct-to-VGPR streams from fragment-packed W),
// + fp32 gating with margin flags + exact fp64 repair.
// T=16384, H=7168, E=256, 8 groups, top4 groups, top8 experts.
// Output (float*): [0..T*8) = topk_idx as float, [T*8..2*T*8) = topk_weight.

typedef __bf16 bf16_t;
typedef __bf16 bf16x4 __attribute__((ext_vector_type(4)));
typedef __bf16 bf16x8 __attribute__((ext_vector_type(8)));
typedef float  f32x4  __attribute__((ext_vector_type(4)));

constexpr int T_TOT = 16384;
constexpr int HID   = 7168;
constexpr int NEXP  = 256;

constexpr int BM1  = 64;
constexpr int BK1  = 32;
constexpr int NCH1 = HID / BK1;   // 224
constexpr int LSTR = 264;         // logits LDS row stride (f32)

// margin thresholds (score scale); bf16x3+fp32-acc score sigma ~2.5e-7 -> ~50x.
constexpr float ETHR = 1.2e-5f;
constexpr float GTHR = 2.4e-5f;

constexpr int LISTCAP = 16384;
constexpr int KSEG = 16;
constexpr int SEGK = HID / KSEG;  // 448
constexpr int TB2  = 32;          // tokens per repair_partial block
constexpr int TBG  = 8;           // tokens per repair_gate block

// ---------------------------------------------------------------------------
__device__ __forceinline__ void cvt8(float4 a, float4 b, bf16x8& h, bf16x8& l)
{
    float f[8] = {a.x, a.y, a.z, a.w, b.x, b.y, b.z, b.w};
#pragma unroll
    for (int j = 0; j < 8; ++j) {
        bf16_t hh = (bf16_t)f[j];
        h[j] = hh;
        l[j] = (bf16_t)(f[j] - (float)hh);
    }
}

// ---------------------------------------------------------------------------
// Kernel 0: pack W fp32 -> bf16 hi/lo in MFMA-fragment order:
//   wpk[c][f][s][8] : e = f*16 + (s&15), k = c*32 + (s>>4)*8 + j
// ---------------------------------------------------------------------------
__global__ __launch_bounds__(256)
void prep_w(const float* __restrict__ w, bf16_t* __restrict__ whi,
            bf16_t* __restrict__ wlo)
{
    const int gid = blockIdx.x * 256 + threadIdx.x;   // 229376
    const int c = gid >> 10;
    const int r = gid & 1023;
    const int f = r >> 6;
    const int s = r & 63;
    const int e  = f * 16 + (s & 15);
    const int k0 = c * 32 + (s >> 4) * 8;

    float4 f0 = *(const float4*)(w + (long)e * HID + k0);
    float4 f1 = *(const float4*)(w + (long)e * HID + k0 + 4);
    bf16x8 hv, lv;
    cvt8(f0, f1, hv, lv);
    *(bf16x8*)(whi + (long)gid * 8) = hv;   // fully coalesced
    *(bf16x8*)(wlo + (long)gid * 8) = lv;
}

// ---------------------------------------------------------------------------
// Kernel 1: MFMA gate + flags. 256 blocks x 512 threads (8 waves, 2m x 4n).
// K-loop: no LDS, no barriers. Each wave streams its own A/B fragments.
// ---------------------------------------------------------------------------
__global__ __launch_bounds__(512, 2)
void gate_mfma(const float* __restrict__ x, const bf16_t* __restrict__ whi_p,
               const bf16_t* __restrict__ wlo_p, const float* __restrict__ bias,
               float* __restrict__ out, int* __restrict__ cnt,
               int* __restrict__ list)
{
    __shared__ __align__(16) float lgl[BM1 * LSTR];   // epilogue only (67584 B)

    const int tid = threadIdx.x;
    const int bid = blockIdx.x;
    const int swz = (bid & 7) * 32 + (bid >> 3);   // XCD swizzle, 256%8==0
    const long trow0 = (long)swz * BM1;

    const int lane = tid & 63;
    const int wid  = tid >> 6;
    const int mw = wid >> 2;      // 0..1 (32 token rows each)
    const int nw = wid & 3;       // 0..3 (64 experts each)

    // A fragment source: lane -> row (lane&15), k-octet (lane>>4)
    const float* xa0 = x + (trow0 + mw * 32 + (lane & 15)) * (long)HID + (lane >> 4) * 8;
    const float* xa1 = xa0 + 16 * (long)HID;
    // B fragment source (element offsets into packed [c][frag][lane][8])
    const long bofs = (long)(nw * 4) * 512 + lane * 8;

    f32x4 acc[2][4] = {};

    float4 pE[4], pO[4];
    bf16x8 bhE[4], blE[4], bhO[4], blO[4];

    auto loadset = [&](int c, float4 (&P)[4], bf16x8 (&BH)[4], bf16x8 (&BL)[4]) {
        const long cb = (long)c * 16 * 512 + bofs;
#pragma unroll
        for (int ni = 0; ni < 4; ++ni) {
            BH[ni] = *(const bf16x8*)(whi_p + cb + ni * 512);
            BL[ni] = *(const bf16x8*)(wlo_p + cb + ni * 512);
        }
        P[0] = *(const float4*)(xa0 + c * BK1);
        P[1] = *(const float4*)(xa0 + c * BK1 + 4);
        P[2] = *(const float4*)(xa1 + c * BK1);
        P[3] = *(const float4*)(xa1 + c * BK1 + 4);
    };

    auto body = [&](int c, float4 (&P)[4], bf16x8 (&BH)[4], bf16x8 (&BL)[4]) {
        bf16x8 ah0, al0, ah1, al1;
        cvt8(P[0], P[1], ah0, al0);
        cvt8(P[2], P[3], ah1, al1);
        __builtin_amdgcn_s_setprio(1);
#pragma unroll
        for (int ni = 0; ni < 4; ++ni) {
            acc[0][ni] = __builtin_amdgcn_mfma_f32_16x16x32_bf16(ah0, BH[ni], acc[0][ni], 0, 0, 0);
            acc[1][ni] = __builtin_amdgcn_mfma_f32_16x16x32_bf16(ah1, BH[ni], acc[1][ni], 0, 0, 0);
        }
#pragma unroll
        for (int ni = 0; ni < 4; ++ni) {
            acc[0][ni] = __builtin_amdgcn_mfma_f32_16x16x32_bf16(ah0, BL[ni], acc[0][ni], 0, 0, 0);
            acc[1][ni] = __builtin_amdgcn_mfma_f32_16x16x32_bf16(ah1, BL[ni], acc[1][ni], 0, 0, 0);
        }
#pragma unroll
        for (int ni = 0; ni < 4; ++ni) {
            acc[0][ni] = __builtin_amdgcn_mfma_f32_16x16x32_bf16(al0, BH[ni], acc[0][ni], 0, 0, 0);
            acc[1][ni] = __builtin_amdgcn_mfma_f32_16x16x32_bf16(al1, BH[ni], acc[1][ni], 0, 0, 0);
        }
        __builtin_amdgcn_s_setprio(0);
        if (c + 2 < NCH1) loadset(c + 2, P, BH, BL);   // one full phase of cover
    };

    // prologue: two chunk-sets in flight
    loadset(0, pE, bhE, blE);
    loadset(1, pO, bhO, blO);

    for (int c = 0; c < NCH1; c += 2) {
        body(c,     pE, bhE, blE);
        body(c + 1, pO, bhO, blO);
    }

    // ---- epilogue: logits -> LDS ----
#pragma unroll
    for (int mi = 0; mi < 2; ++mi)
#pragma unroll
        for (int ni = 0; ni < 4; ++ni)
#pragma unroll
            for (int r = 0; r < 4; ++r)
                lgl[(mw * 32 + mi * 16 + (lane >> 4) * 4 + r) * LSTR +
                    nw * 64 + ni * 16 + (lane & 15)] = acc[mi][ni][r];
    __syncthreads();

    // ---- gating (proven fp32) + margin flags; half-wave = 4 tokens ----
    const int l     = tid & 31;
    const int hbase = lane & 32;
    const int myGLo = l >> 3;
    const int m0    = (tid >> 5) * 4;   // 16 half-waves x 4 tokens

    float bb[8];
    {
        float4 b0 = *(const float4*)&bias[4 * l];
        float4 b1 = *(const float4*)&bias[4 * l + 128];
        bb[0] = b0.x; bb[1] = b0.y; bb[2] = b0.z; bb[3] = b0.w;
        bb[4] = b1.x; bb[5] = b1.y; bb[6] = b1.z; bb[7] = b1.w;
    }

    float* out_idx = out;
    float* out_w   = out + (long)T_TOT * 8;

    for (int i = 0; i < 4; ++i) {
        const long t = trow0 + m0 + i;
        float4 lg0 = *(const float4*)&lgl[(m0 + i) * LSTR + 4 * l];
        float4 lg1 = *(const float4*)&lgl[(m0 + i) * LSTR + 128 + 4 * l];
        float lgv[8] = {lg0.x, lg0.y, lg0.z, lg0.w, lg1.x, lg1.y, lg1.z, lg1.w};
        float sc[8], cs[8];
#pragma unroll
        for (int j = 0; j < 8; ++j) {
            sc[j] = 1.0f / (1.0f + expf(-lgv[j]));
            cs[j] = sc[j] + bb[j];
        }
        float l1, l2, h1, h2;
        {
            l1 = fmaxf(cs[0], cs[1]); l2 = fminf(cs[0], cs[1]);
            float n1 = fmaxf(l1, cs[2]); float n2 = fmaxf(fminf(l1, cs[2]), l2); l1 = n1; l2 = n2;
            n1 = fmaxf(l1, cs[3]); n2 = fmaxf(fminf(l1, cs[3]), l2); l1 = n1; l2 = n2;
            h1 = fmaxf(cs[4], cs[5]); h2 = fminf(cs[4], cs[5]);
            n1 = fmaxf(h1, cs[6]); n2 = fmaxf(fminf(h1, cs[6]), h2); h1 = n1; h2 = n2;
            n1 = fmaxf(h1, cs[7]); n2 = fmaxf(fminf(h1, cs[7]), h2); h1 = n1; h2 = n2;
        }
#pragma unroll
        for (int d = 1; d < 8; d <<= 1) {
            float o1 = __shfl_xor(l1, d), o2 = __shfl_xor(l2, d);
            float n1 = fmaxf(l1, o1);
            float n2 = fmaxf(fminf(l1, o1), fmaxf(l2, o2));
            l1 = n1; l2 = n2;
            o1 = __shfl_xor(h1, d); o2 = __shfl_xor(h2, d);
            n1 = fmaxf(h1, o1);
            n2 = fmaxf(fminf(h1, o1), fmaxf(h2, o2));
            h1 = n1; h2 = n2;
        }
        const float gLo = l1 + l2;
        const float gHi = h1 + h2;

        int rLo = 0, rHi = 0;
#pragma unroll
        for (int g = 0; g < 8; ++g) {
            float v = (g < 4) ? __shfl(gLo, hbase + g * 8)
                              : __shfl(gHi, hbase + (g - 4) * 8);
            rLo += (v > gLo || (v == gLo && g < myGLo)) ? 1 : 0;
            rHi += (v > gHi || (v == gHi && g < myGLo + 4)) ? 1 : 0;
        }
        const bool selLo = (rLo < 4);
        const bool selHi = (rHi < 4);

        float selMin =  INFINITY, unsMax = -INFINITY;
        if (selLo) selMin = gLo; else unsMax = gLo;
        if (selHi) selMin = fminf(selMin, gHi); else unsMax = fmaxf(unsMax, gHi);
#pragma unroll
        for (int d = 1; d < 32; d <<= 1) {
            selMin = fminf(selMin, __shfl_xor(selMin, d));
            unsMax = fmaxf(unsMax, __shfl_xor(unsMax, d));
        }
        const float ggap = selMin - unsMax;

        float mv[8];
#pragma unroll
        for (int j = 0; j < 8; ++j)
            mv[j] = ((j < 4) ? selLo : selHi) ? cs[j] : -INFINITY;

        float wsum = 0.0f, my_w = 0.0f;
        int my_ii = 0;
        float prevv = 0.0f, mingap = INFINITY;
#pragma unroll
        for (int k = 0; k < 9; ++k) {
            float bv = mv[0]; int bj = 0;
            if (mv[1] > bv) { bv = mv[1]; bj = 1; }
            if (mv[2] > bv) { bv = mv[2]; bj = 2; }
            if (mv[3] > bv) { bv = mv[3]; bj = 3; }
            if (mv[4] > bv) { bv = mv[4]; bj = 4; }
            if (mv[5] > bv) { bv = mv[5]; bj = 5; }
            if (mv[6] > bv) { bv = mv[6]; bj = 6; }
            if (mv[7] > bv) { bv = mv[7]; bj = 7; }
            float v = bv;
            int ii = (bj < 4) ? (4 * l + bj) : (128 + 4 * l + (bj - 4));
#pragma unroll
            for (int d = 1; d < 32; d <<= 1) {
                float ov = __shfl_xor(v, d);
                int   oi = __shfl_xor(ii, d);
                if (ov > v || (ov == v && oi < ii)) { v = ov; ii = oi; }
            }
            if (k) mingap = fminf(mingap, prevv - v);
            prevv = v;
            if (k < 8) {
                const int hi8 = ii >> 7;
                const int oj  = (ii & 3) + 4 * hi8;
                const int ol  = (ii & 127) >> 2;
                float ssel = (oj == 0) ? sc[0] : (oj == 1) ? sc[1] : (oj == 2) ? sc[2] :
                             (oj == 3) ? sc[3] : (oj == 4) ? sc[4] : (oj == 5) ? sc[5] :
                             (oj == 6) ? sc[6] : sc[7];
                float su = __shfl(ssel, hbase + ol);
                wsum += su;
                if (l == k) { my_ii = ii; my_w = su; }
#pragma unroll
                for (int j = 0; j < 8; ++j) {
                    int jj = (j < 4) ? (4 * l + j) : (128 + 4 * l + (j - 4));
                    if (jj == ii) mv[j] = -INFINITY;
                }
            }
        }

        const float scale = 2.5f / (wsum + 1e-20f);
        if (l < 8) {
            out_idx[t * 8 + l] = (float)my_ii;
            out_w[t * 8 + l]   = my_w * scale;
        }
        const bool flag = (mingap < ETHR) || (ggap < GTHR);
        if (flag && l == 0) {
            int pos = atomicAdd(cnt, 1);
            if (pos < LISTCAP) list[pos] = (int)t;
        }
    }
}

// ---------------------------------------------------------------------------
// Kernel 2: fp64 partial dots for flagged tokens (K-split, 32 tokens/block)
// ---------------------------------------------------------------------------
__global__ __launch_bounds__(256)
void repair_partial(const float* __restrict__ x, const float* __restrict__ w,
                    const int* __restrict__ list, const int* __restrict__ cntp,
                    double* __restrict__ part, int base, int cap)
{
    __shared__ __align__(16) float xls[TB2 * SEGK];   // 57344 B
    __shared__ int tokls[TB2];
    const int tid = threadIdx.x;
    const int ks  = blockIdx.y;

    int cnt = *cntp;
    if (cnt > 2 * cap)  cnt = 2 * cap;
    if (cnt > LISTCAP)  cnt = LISTCAP;
    const int cEnd = min(cnt, base + cap);

    for (int s0 = base + blockIdx.x * TB2; s0 < cEnd; s0 += gridDim.x * TB2) {
        if (tid < TB2) {
            int slot = s0 + tid;
            tokls[tid] = (slot < cEnd) ? list[slot] : 0;
        }
        __syncthreads();
        for (int q = tid; q < TB2 * (SEGK / 4); q += 256) {
            int i = q / (SEGK / 4), f = q % (SEGK / 4);
            float4 v = *(const float4*)(x + (long)tokls[i] * HID + ks * SEGK + f * 4);
            *(float4*)&xls[i * SEGK + f * 4] = v;
        }
        __syncthreads();

        double acc[TB2];
#pragma unroll
        for (int i = 0; i < TB2; ++i) acc[i] = 0.0;

        const float4* wp = (const float4*)(w + (long)tid * HID + ks * SEGK);
        for (int kb = 0; kb < SEGK / 4; ++kb) {
            float4 wv = wp[kb];
            double w0 = wv.x, w1 = wv.y, w2 = wv.z, w3 = wv.w;
#pragma unroll
            for (int i = 0; i < TB2; ++i) {
                float4 xv = *(const float4*)&xls[i * SEGK + kb * 4];
                acc[i] = fma((double)xv.x, w0, acc[i]);
                acc[i] = fma((double)xv.y, w1, acc[i]);
                acc[i] = fma((double)xv.z, w2, acc[i]);
                acc[i] = fma((double)xv.w, w3, acc[i]);
            }
        }
#pragma unroll
        for (int i = 0; i < TB2; ++i) {
            long pofs = (((long)(s0 - base) + i) * KSEG + ks) * NEXP + tid;
            part[pofs] = acc[i];
        }
        __syncthreads();
    }
}

// ---------------------------------------------------------------------------
// Kernel 3: reduce partials + exact fp64 gating for flagged tokens
// ---------------------------------------------------------------------------
__global__ __launch_bounds__(256)
void repair_gate(const float* __restrict__ bias, const int* __restrict__ list,
                 const int* __restrict__ cntp, const double* __restrict__ part,
                 float* __restrict__ out, int base, int cap)
{
    __shared__ double lgl[TBG * NEXP];
    __shared__ int tokls[TBG];
    const int tid = threadIdx.x;

    int cnt = *cntp;
    if (cnt > 2 * cap)  cnt = 2 * cap;
    if (cnt > LISTCAP)  cnt = LISTCAP;
    const int cEnd = min(cnt, base + cap);

    float* out_idx = out;
    float* out_w   = out + (long)T_TOT * 8;

    const int l     = tid & 31;
    const int lane  = tid & 63;
    const int hbase = lane & 32;
    const int hw    = tid >> 5;
    const int myGLo = l >> 3;

    double bb[8];
    {
        float4 b0 = *(const float4*)&bias[4 * l];
        float4 b1 = *(const float4*)&bias[4 * l + 128];
        bb[0] = b0.x; bb[1] = b0.y; bb[2] = b0.z; bb[3] = b0.w;
        bb[4] = b1.x; bb[5] = b1.y; bb[6] = b1.z; bb[7] = b1.w;
    }

    for (int s0 = base + blockIdx.x * TBG; s0 < cEnd; s0 += gridDim.x * TBG) {
        if (tid < TBG) {
            int slot = s0 + tid;
            tokls[tid] = (slot < cEnd) ? list[slot] : 0;
        }
#pragma unroll
        for (int i = 0; i < TBG; ++i) {
            long pbase = (((long)(s0 - base) + i) * KSEG) * NEXP + tid;
            double s = 0.0;
#pragma unroll
            for (int ks = 0; ks < KSEG; ++ks) s += part[pbase + ks * NEXP];
            lgl[i * NEXP + tid] = s;
        }
        __syncthreads();
        {
            const int slot = s0 + hw;
            const bool valid = (slot < cEnd);
            const long t = tokls[hw];

            double sc[8], cs[8];
#pragma unroll
            for (int j = 0; j < 4; ++j) {
                double lg = lgl[hw * NEXP + 4 * l + j];
                sc[j] = 1.0 / (1.0 + exp(-lg));
                cs[j] = sc[j] + bb[j];
            }
#pragma unroll
            for (int j = 4; j < 8; ++j) {
                double lg = lgl[hw * NEXP + 128 + 4 * l + (j - 4)];
                sc[j] = 1.0 / (1.0 + exp(-lg));
                cs[j] = sc[j] + bb[j];
            }

            double l1, l2, h1, h2;
            {
                l1 = fmax(cs[0], cs[1]); l2 = fmin(cs[0], cs[1]);
                double n1 = fmax(l1, cs[2]); double n2 = fmax(fmin(l1, cs[2]), l2); l1 = n1; l2 = n2;
                n1 = fmax(l1, cs[3]); n2 = fmax(fmin(l1, cs[3]), l2); l1 = n1; l2 = n2;
                h1 = fmax(cs[4], cs[5]); h2 = fmin(cs[4], cs[5]);
                n1 = fmax(h1, cs[6]); n2 = fmax(fmin(h1, cs[6]), h2); h1 = n1; h2 = n2;
                n1 = fmax(h1, cs[7]); n2 = fmax(fmin(h1, cs[7]), h2); h1 = n1; h2 = n2;
            }
#pragma unroll
            for (int d = 1; d < 8; d <<= 1) {
                double o1 = __shfl_xor(l1, d), o2 = __shfl_xor(l2, d);
                double n1 = fmax(l1, o1);
                double n2 = fmax(fmin(l1, o1), fmax(l2, o2));
                l1 = n1; l2 = n2;
                o1 = __shfl_xor(h1, d); o2 = __shfl_xor(h2, d);
                n1 = fmax(h1, o1);
                n2 = fmax(fmin(h1, o1), fmax(h2, o2));
                h1 = n1; h2 = n2;
            }
            const double gLo = l1 + l2;
            const double gHi = h1 + h2;

            int rLo = 0, rHi = 0;
#pragma unroll
            for (int g = 0; g < 8; ++g) {
                double v = (g < 4) ? __shfl(gLo, hbase + g * 8)
                                   : __shfl(gHi, hbase + (g - 4) * 8);
                rLo += (v > gLo || (v == gLo && g < myGLo)) ? 1 : 0;
                rHi += (v > gHi || (v == gHi && g < myGLo + 4)) ? 1 : 0;
            }
            const bool selLo = (rLo < 4);
            const bool selHi = (rHi < 4);

            double mv[8];
#pragma unroll
            for (int j = 0; j < 8; ++j)
                mv[j] = ((j < 4) ? selLo : selHi) ? cs[j] : -INFINITY;

            double wsum = 0.0, my_w = 0.0;
            int my_ii = 0;
#pragma unroll
            for (int k = 0; k < 8; ++k) {
                double bv = mv[0]; int bj = 0;
                if (mv[1] > bv) { bv = mv[1]; bj = 1; }
                if (mv[2] > bv) { bv = mv[2]; bj = 2; }
                if (mv[3] > bv) { bv = mv[3]; bj = 3; }
                if (mv[4] > bv) { bv = mv[4]; bj = 4; }
                if (mv[5] > bv) { bv = mv[5]; bj = 5; }
                if (mv[6] > bv) { bv = mv[6]; bj = 6; }
                if (mv[7] > bv) { bv = mv[7]; bj = 7; }
                double v = bv;
                int ii = (bj < 4) ? (4 * l + bj) : (128 + 4 * l + (bj - 4));
#pragma unroll
                for (int d = 1; d < 32; d <<= 1) {
                    double ov = __shfl_xor(v, d);
                    int    oi = __shfl_xor(ii, d);
                    if (ov > v || (ov == v && oi < ii)) { v = ov; ii = oi; }
                }
                const int hi8 = ii >> 7;
                const int oj  = (ii & 3) + 4 * hi8;
                const int ol  = (ii & 127) >> 2;
                double ssel = (oj == 0) ? sc[0] : (oj == 1) ? sc[1] : (oj == 2) ? sc[2] :
                              (oj == 3) ? sc[3] : (oj == 4) ? sc[4] : (oj == 5) ? sc[5] :
                              (oj == 6) ? sc[6] : sc[7];
                double su = __shfl(ssel, hbase + ol);
                wsum += su;
                if (l == k) { my_ii = ii; my_w = su; }
#pragma unroll
                for (int j = 0; j < 8; ++j) {
                    int jj = (j < 4) ? (4 * l + j) : (128 + 4 * l + (j - 4));
                    if (jj == ii) mv[j] = -INFINITY;
                }
            }

            const double scale = 2.5 / (wsum + 1e-20);
            if (valid && l < 8) {
                out_idx[t * 8 + l] = (float)my_ii;
                out_w[t * 8 + l]   = (float)(my_w * scale);
            }
        }
        __syncthreads();
    }
}

// ---------------------------------------------------------------------------
extern "C" void kernel_launch(void* const* d_in, const int* in_sizes, int n_in,
                              void* d_out, int out_size, void* d_ws, size_t ws_size,
                              hipStream_t stream)
{
    const float* x    = (const float*)d_in[0];
    const float* w    = (const float*)d_in[1];
    const float* bias = (const float*)d_in[2];
    float* out = (float*)d_out;

    int*    cnt  = (int*)d_ws;                          // [0,256)
    int*    list = (int*)((char*)d_ws + 256);           // 64 KB
    bf16_t* whi  = (bf16_t*)((char*)d_ws + 66048);      // 3,670,016 B
    bf16_t* wlo  = (bf16_t*)((char*)d_ws + 66048 + 3670016);
    double* part = (double*)((char*)d_ws + 7406080);

    size_t avail = (ws_size > 7406080) ? (ws_size - 7406080) : 0;
    long cap_l = (long)(avail / ((size_t)KSEG * NEXP * 8));   // 32 KB per slot
    int CAP = (int)(cap_l > 4096 ? 4096 : cap_l);

    hipMemsetAsync(d_ws, 0, 4, stream);
    prep_w<<<896, 256, 0, stream>>>(w, whi, wlo);
    gate_mfma<<<256, 512, 0, stream>>>(x, whi, wlo, bias, out, cnt, list);
    if (CAP > 0) {
        for (int p = 0; p < 2; ++p) {
            repair_partial<<<dim3(32, KSEG), 256, 0, stream>>>(x, w, list, cnt, part, p * CAP, CAP);
            repair_gate<<<64, 256, 0, stream>>>(bias, list, cnt, part, out, p * CAP, CAP);
        }
    }
}

// Round 10
// 444.914 us; speedup vs baseline: 1.3769x; 1.3769x over previous
//
#include <hip/hip_runtime.h>
#include <math.h>

// MoE gate: bf16x3 split MFMA GEMM with K=64 barrier phases (2 chunks/phase,
// 2x64KB B double-buffer via global_load_lds + 2x16KB cooperative A buffers),
// + fp32 gating with margin flags + exact fp64 repair.
// T=16384, H=7168, E=256, 8 groups, top4 groups, top8 experts.
// Output (float*): [0..T*8) = topk_idx as float, [T*8..2*T*8) = topk_weight.

typedef __bf16 bf16_t;
typedef __bf16 bf16x4 __attribute__((ext_vector_type(4)));
typedef __bf16 bf16x8 __attribute__((ext_vector_type(8)));
typedef float  f32x4  __attribute__((ext_vector_type(4)));

constexpr int T_TOT = 16384;
constexpr int HID   = 7168;
constexpr int NEXP  = 256;

constexpr int BM1  = 64;
constexpr int BK1  = 32;
constexpr int NCH1 = HID / BK1;   // 224
constexpr int NPH  = NCH1 / 2;    // 112 phases of K=64

// LDS: B 2 phase-bufs x 64 KB (2 chunk-subs x [hi 16K | lo 16K]),
//      A 2 phase-bufs x 16 KB (2 chunk-subs x [hi 4K | lo 4K]).
// Epilogue alias: logits f32 [64][264] = 67584 B over B region.
constexpr int B_PH    = 65536;
constexpr int A_OFF   = 131072;
constexpr int A_PH    = 16384;
constexpr int SMEM_SZ = 163840;
constexpr int LSTR    = 264;

// margin thresholds (score scale); bf16x3+fp32-acc score sigma ~2.5e-7 -> ~50x.
constexpr float ETHR = 1.2e-5f;
constexpr float GTHR = 2.4e-5f;

constexpr int LISTCAP = 16384;
constexpr int KSEG = 16;
constexpr int SEGK = HID / KSEG;  // 448
constexpr int TB2  = 32;          // tokens per repair_partial block
constexpr int TBG  = 8;           // tokens per repair_gate block

// ---------------------------------------------------------------------------
__device__ __forceinline__ void async16(const void* g, void* l)
{
    auto* lds = reinterpret_cast<__attribute__((address_space(3))) unsigned int*>(
        reinterpret_cast<uintptr_t>(l));
    const auto* gl = reinterpret_cast<const __attribute__((address_space(1))) unsigned int*>(
        reinterpret_cast<uintptr_t>(g));
    __builtin_amdgcn_global_load_lds(gl, lds, 16, 0, 0);
}

__device__ __forceinline__ void cvt4(float4 v, bf16x4& h, bf16x4& l)
{
    bf16_t h0 = (bf16_t)v.x, h1 = (bf16_t)v.y, h2 = (bf16_t)v.z, h3 = (bf16_t)v.w;
    h = bf16x4{h0, h1, h2, h3};
    l = bf16x4{(bf16_t)(v.x - (float)h0), (bf16_t)(v.y - (float)h1),
               (bf16_t)(v.z - (float)h2), (bf16_t)(v.w - (float)h3)};
}

// ---------------------------------------------------------------------------
// Kernel 0: pack W fp32 -> bf16 hi/lo in MFMA-fragment order:
//   wpk[c][f][s][8] : e = f*16 + (s&15), k = c*32 + (s>>4)*8 + j
// ---------------------------------------------------------------------------
__global__ __launch_bounds__(256)
void prep_w(const float* __restrict__ w, bf16_t* __restrict__ whi,
            bf16_t* __restrict__ wlo)
{
    const int gid = blockIdx.x * 256 + threadIdx.x;   // 229376
    const int c = gid >> 10;
    const int r = gid & 1023;
    const int f = r >> 6;
    const int s = r & 63;
    const int e  = f * 16 + (s & 15);
    const int k0 = c * 32 + (s >> 4) * 8;

    float4 f0 = *(const float4*)(w + (long)e * HID + k0);
    float4 f1 = *(const float4*)(w + (long)e * HID + k0 + 4);
    bf16x4 h0, l0, h1, l1;
    cvt4(f0, h0, l0);
    cvt4(f1, h1, l1);
    bf16x8 hv = {h0[0], h0[1], h0[2], h0[3], h1[0], h1[1], h1[2], h1[3]};
    bf16x8 lv = {l0[0], l0[1], l0[2], l0[3], l1[0], l1[1], l1[2], l1[3]};
    *(bf16x8*)(whi + (long)gid * 8) = hv;   // fully coalesced
    *(bf16x8*)(wlo + (long)gid * 8) = lv;
}

// ---------------------------------------------------------------------------
__device__ __forceinline__ void stage_B(int c, char* bbuf,
                                        const bf16_t* whi_p, const bf16_t* wlo_p,
                                        int wid, int lane)
{
    const int f0 = wid * 2;   // wave stages frags f0, f0+1 (hi+lo)
    const long base = (((long)c * 16 + f0) * 64 + lane) * 8;
    const bf16_t* sh = whi_p + base;
    const bf16_t* sl = wlo_p + base;
    char* dh = bbuf + f0 * 1024;
    char* dl = bbuf + 16384 + f0 * 1024;
    async16(sh,       dh);
    async16(sh + 512, dh + 1024);
    async16(sl,       dl);
    async16(sl + 512, dl + 1024);
}

// ---------------------------------------------------------------------------
// Kernel 1: MFMA gate + flags. 256 blocks x 512 threads (8 waves, 2m x 4n).
// ---------------------------------------------------------------------------
__global__ __launch_bounds__(512, 2)
void gate_mfma(const float* __restrict__ x, const bf16_t* __restrict__ whi_p,
               const bf16_t* __restrict__ wlo_p, const float* __restrict__ bias,
               float* __restrict__ out, int* __restrict__ cnt,
               int* __restrict__ list)
{
    extern __shared__ __align__(16) char smem[];

    const int tid = threadIdx.x;
    const int bid = blockIdx.x;
    const int swz = (bid & 7) * 32 + (bid >> 3);   // XCD swizzle, 256%8==0
    const long trow0 = (long)swz * BM1;

    const int lane = tid & 63;
    const int wid  = tid >> 6;
    const int mw = wid >> 2;      // 0..1 (32 token rows each)
    const int nw = wid & 3;       // 0..3 (64 experts each)

    // A cooperative map: thread tid ds_writes at byte tid*8 (linear);
    // inverse: row = (tid>>7)*16 + ((tid>>1)&15), k0 = ((tid>>5)&3)*8 + (tid&1)*4
    const int arow = (tid >> 7) * 16 + ((tid >> 1) & 15);
    const int ak0  = ((tid >> 5) & 3) * 8 + (tid & 1) * 4;
    const float* xsrc = x + (trow0 + arow) * (long)HID + ak0;

    f32x4 acc[2][4] = {};
    float4 pN0, pN1;   // A regs for phase p+1 (chunks 2p+2, 2p+3)

    // ---- prologue ----
    {
        float4 pC0 = *(const float4*)(xsrc);
        float4 pC1 = *(const float4*)(xsrc + BK1);
        asm volatile("" ::: "memory");
        stage_B(0, smem,         whi_p, wlo_p, wid, lane);
        stage_B(1, smem + 32768, whi_p, wlo_p, wid, lane);
        asm volatile("" ::: "memory");
        pN0 = *(const float4*)(xsrc + 2 * BK1);
        pN1 = *(const float4*)(xsrc + 3 * BK1);
        asm volatile("s_waitcnt vmcnt(2)" ::: "memory");   // drain pC + B(phase0)
        bf16x4 h, l;
        char* aw = smem + A_OFF;
        cvt4(pC0, h, l);
        *(bf16x4*)(aw + tid * 8)        = h;
        *(bf16x4*)(aw + 4096 + tid * 8) = l;
        cvt4(pC1, h, l);
        *(bf16x4*)(aw + 8192 + tid * 8)  = h;
        *(bf16x4*)(aw + 12288 + tid * 8) = l;
        asm volatile("s_waitcnt lgkmcnt(0)" ::: "memory");
        __builtin_amdgcn_s_barrier();
    }

    // ---- phase loop: 112 phases of K=64 ----
    for (int p = 0; p < NPH; ++p) {
        if (p) {
            asm volatile("s_waitcnt vmcnt(0) lgkmcnt(0)" ::: "memory");
            __builtin_amdgcn_s_barrier();
        }
        // write A(p+1) from regs; stage B(p+1); reload A regs for p+2
        if (p + 1 < NPH) {
            bf16x4 h, l;
            char* aw = smem + A_OFF + ((p + 1) & 1) * A_PH;
            cvt4(pN0, h, l);
            *(bf16x4*)(aw + tid * 8)        = h;
            *(bf16x4*)(aw + 4096 + tid * 8) = l;
            cvt4(pN1, h, l);
            *(bf16x4*)(aw + 8192 + tid * 8)  = h;
            *(bf16x4*)(aw + 12288 + tid * 8) = l;
            asm volatile("" ::: "memory");
            char* bw = smem + ((p + 1) & 1) * B_PH;
            stage_B(2 * p + 2, bw,         whi_p, wlo_p, wid, lane);
            stage_B(2 * p + 3, bw + 32768, whi_p, wlo_p, wid, lane);
            asm volatile("" ::: "memory");
        }
        if (p + 2 < NPH) {
            pN0 = *(const float4*)(xsrc + (2 * p + 4) * BK1);
            pN1 = *(const float4*)(xsrc + (2 * p + 5) * BK1);
        }

        // compute the two chunks of phase p
        const char* bP = smem + (p & 1) * B_PH;
        const char* aP = smem + A_OFF + (p & 1) * A_PH;
#pragma unroll
        for (int s = 0; s < 2; ++s) {
            const char* aB = aP + s * 8192;
            const char* bB = bP + s * 32768;
            bf16x8 ah[2], al[2], bh[4], bl[4];
#pragma unroll
            for (int mi = 0; mi < 2; ++mi) {
                ah[mi] = *(const bf16x8*)(aB + (mw * 2 + mi) * 1024 + lane * 16);
                al[mi] = *(const bf16x8*)(aB + 4096 + (mw * 2 + mi) * 1024 + lane * 16);
            }
#pragma unroll
            for (int ni = 0; ni < 4; ++ni) {
                bh[ni] = *(const bf16x8*)(bB + (nw * 4 + ni) * 1024 + lane * 16);
                bl[ni] = *(const bf16x8*)(bB + 16384 + (nw * 4 + ni) * 1024 + lane * 16);
            }
            __builtin_amdgcn_s_setprio(1);
#pragma unroll
            for (int ni = 0; ni < 4; ++ni) {
                acc[0][ni] = __builtin_amdgcn_mfma_f32_16x16x32_bf16(ah[0], bh[ni], acc[0][ni], 0, 0, 0);
                acc[1][ni] = __builtin_amdgcn_mfma_f32_16x16x32_bf16(ah[1], bh[ni], acc[1][ni], 0, 0, 0);
            }
#pragma unroll
            for (int ni = 0; ni < 4; ++ni) {
                acc[0][ni] = __builtin_amdgcn_mfma_f32_16x16x32_bf16(ah[0], bl[ni], acc[0][ni], 0, 0, 0);
                acc[1][ni] = __builtin_amdgcn_mfma_f32_16x16x32_bf16(ah[1], bl[ni], acc[1][ni], 0, 0, 0);
            }
#pragma unroll
            for (int ni = 0; ni < 4; ++ni) {
                acc[0][ni] = __builtin_amdgcn_mfma_f32_16x16x32_bf16(al[0], bh[ni], acc[0][ni], 0, 0, 0);
                acc[1][ni] = __builtin_amdgcn_mfma_f32_16x16x32_bf16(al[1], bh[ni], acc[1][ni], 0, 0, 0);
            }
            __builtin_amdgcn_s_setprio(0);
        }
    }
    __syncthreads();   // all reads done before logits alias

    // ---- epilogue: logits -> LDS ----
    float* lgl = (float*)smem;
#pragma unroll
    for (int mi = 0; mi < 2; ++mi)
#pragma unroll
        for (int ni = 0; ni < 4; ++ni)
#pragma unroll
            for (int r = 0; r < 4; ++r)
                lgl[(mw * 32 + mi * 16 + (lane >> 4) * 4 + r) * LSTR +
                    nw * 64 + ni * 16 + (lane & 15)] = acc[mi][ni][r];
    __syncthreads();

    // ---- gating (proven fp32) + margin flags; half-wave = 4 tokens ----
    const int l     = tid & 31;
    const int hbase = lane & 32;
    const int myGLo = l >> 3;
    const int m0    = (tid >> 5) * 4;   // 16 half-waves x 4 tokens

    float bb[8];
    {
        float4 b0 = *(const float4*)&bias[4 * l];
        float4 b1 = *(const float4*)&bias[4 * l + 128];
        bb[0] = b0.x; bb[1] = b0.y; bb[2] = b0.z; bb[3] = b0.w;
        bb[4] = b1.x; bb[5] = b1.y; bb[6] = b1.z; bb[7] = b1.w;
    }

    float* out_idx = out;
    float* out_w   = out + (long)T_TOT * 8;

    for (int i = 0; i < 4; ++i) {
        const long t = trow0 + m0 + i;
        float4 lg0 = *(const float4*)&lgl[(m0 + i) * LSTR + 4 * l];
        float4 lg1 = *(const float4*)&lgl[(m0 + i) * LSTR + 128 + 4 * l];
        float lgv[8] = {lg0.x, lg0.y, lg0.z, lg0.w, lg1.x, lg1.y, lg1.z, lg1.w};
        float sc[8], cs[8];
#pragma unroll
        for (int j = 0; j < 8; ++j) {
            sc[j] = 1.0f / (1.0f + expf(-lgv[j]));
            cs[j] = sc[j] + bb[j];
        }
        float l1, l2, h1, h2;
        {
            l1 = fmaxf(cs[0], cs[1]); l2 = fminf(cs[0], cs[1]);
            float n1 = fmaxf(l1, cs[2]); float n2 = fmaxf(fminf(l1, cs[2]), l2); l1 = n1; l2 = n2;
            n1 = fmaxf(l1, cs[3]); n2 = fmaxf(fminf(l1, cs[3]), l2); l1 = n1; l2 = n2;
            h1 = fmaxf(cs[4], cs[5]); h2 = fminf(cs[4], cs[5]);
            n1 = fmaxf(h1, cs[6]); n2 = fmaxf(fminf(h1, cs[6]), h2); h1 = n1; h2 = n2;
            n1 = fmaxf(h1, cs[7]); n2 = fmaxf(fminf(h1, cs[7]), h2); h1 = n1; h2 = n2;
        }
#pragma unroll
        for (int d = 1; d < 8; d <<= 1) {
            float o1 = __shfl_xor(l1, d), o2 = __shfl_xor(l2, d);
            float n1 = fmaxf(l1, o1);
            float n2 = fmaxf(fminf(l1, o1), fmaxf(l2, o2));
            l1 = n1; l2 = n2;
            o1 = __shfl_xor(h1, d); o2 = __shfl_xor(h2, d);
            n1 = fmaxf(h1, o1);
            n2 = fmaxf(fminf(h1, o1), fmaxf(h2, o2));
            h1 = n1; h2 = n2;
        }
        const float gLo = l1 + l2;
        const float gHi = h1 + h2;

        int rLo = 0, rHi = 0;
#pragma unroll
        for (int g = 0; g < 8; ++g) {
            float v = (g < 4) ? __shfl(gLo, hbase + g * 8)
                              : __shfl(gHi, hbase + (g - 4) * 8);
            rLo += (v > gLo || (v == gLo && g < myGLo)) ? 1 : 0;
            rHi += (v > gHi || (v == gHi && g < myGLo + 4)) ? 1 : 0;
        }
        const bool selLo = (rLo < 4);
        const bool selHi = (rHi < 4);

        float selMin =  INFINITY, unsMax = -INFINITY;
        if (selLo) selMin = gLo; else unsMax = gLo;
        if (selHi) selMin = fminf(selMin, gHi); else unsMax = fmaxf(unsMax, gHi);
#pragma unroll
        for (int d = 1; d < 32; d <<= 1) {
            selMin = fminf(selMin, __shfl_xor(selMin, d));
            unsMax = fmaxf(unsMax, __shfl_xor(unsMax, d));
        }
        const float ggap = selMin - unsMax;

        float mv[8];
#pragma unroll
        for (int j = 0; j < 8; ++j)
            mv[j] = ((j < 4) ? selLo : selHi) ? cs[j] : -INFINITY;

        float wsum = 0.0f, my_w = 0.0f;
        int my_ii = 0;
        float prevv = 0.0f, mingap = INFINITY;
#pragma unroll
        for (int k = 0; k < 9; ++k) {
            float bv = mv[0]; int bj = 0;
            if (mv[1] > bv) { bv = mv[1]; bj = 1; }
            if (mv[2] > bv) { bv = mv[2]; bj = 2; }
            if (mv[3] > bv) { bv = mv[3]; bj = 3; }
            if (mv[4] > bv) { bv = mv[4]; bj = 4; }
            if (mv[5] > bv) { bv = mv[5]; bj = 5; }
            if (mv[6] > bv) { bv = mv[6]; bj = 6; }
            if (mv[7] > bv) { bv = mv[7]; bj = 7; }
            float v = bv;
            int ii = (bj < 4) ? (4 * l + bj) : (128 + 4 * l + (bj - 4));
#pragma unroll
            for (int d = 1; d < 32; d <<= 1) {
                float ov = __shfl_xor(v, d);
                int   oi = __shfl_xor(ii, d);
                if (ov > v || (ov == v && oi < ii)) { v = ov; ii = oi; }
            }
            if (k) mingap = fminf(mingap, prevv - v);
            prevv = v;
            if (k < 8) {
                const int hi8 = ii >> 7;
                const int oj  = (ii & 3) + 4 * hi8;
                const int ol  = (ii & 127) >> 2;
                float ssel = (oj == 0) ? sc[0] : (oj == 1) ? sc[1] : (oj == 2) ? sc[2] :
                             (oj == 3) ? sc[3] : (oj == 4) ? sc[4] : (oj == 5) ? sc[5] :
                             (oj == 6) ? sc[6] : sc[7];
                float su = __shfl(ssel, hbase + ol);
                wsum += su;
                if (l == k) { my_ii = ii; my_w = su; }
#pragma unroll
                for (int j = 0; j < 8; ++j) {
                    int jj = (j < 4) ? (4 * l + j) : (128 + 4 * l + (j - 4));
                    if (jj == ii) mv[j] = -INFINITY;
                }
            }
        }

        const float scale = 2.5f / (wsum + 1e-20f);
        if (l < 8) {
            out_idx[t * 8 + l] = (float)my_ii;
            out_w[t * 8 + l]   = my_w * scale;
        }
        const bool flag = (mingap < ETHR) || (ggap < GTHR);
        if (flag && l == 0) {
            int pos = atomicAdd(cnt, 1);
            if (pos < LISTCAP) list[pos] = (int)t;
        }
    }
}

// ---------------------------------------------------------------------------
// Kernel 2: fp64 partial dots for flagged tokens (K-split, 32 tokens/block)
// ---------------------------------------------------------------------------
__global__ __launch_bounds__(256)
void repair_partial(const float* __restrict__ x, const float* __restrict__ w,
                    const int* __restrict__ list, const int* __restrict__ cntp,
                    double* __restrict__ part, int base, int cap)
{
    __shared__ __align__(16) float xls[TB2 * SEGK];   // 57344 B
    __shared__ int tokls[TB2];
    const int tid = threadIdx.x;
    const int ks  = blockIdx.y;

    int cnt = *cntp;
    if (cnt > 2 * cap)  cnt = 2 * cap;
    if (cnt > LISTCAP)  cnt = LISTCAP;
    const int cEnd = min(cnt, base + cap);

    for (int s0 = base + blockIdx.x * TB2; s0 < cEnd; s0 += gridDim.x * TB2) {
        if (tid < TB2) {
            int slot = s0 + tid;
            tokls[tid] = (slot < cEnd) ? list[slot] : 0;
        }
        __syncthreads();
        for (int q = tid; q < TB2 * (SEGK / 4); q += 256) {
            int i = q / (SEGK / 4), f = q % (SEGK / 4);
            float4 v = *(const float4*)(x + (long)tokls[i] * HID + ks * SEGK + f * 4);
            *(float4*)&xls[i * SEGK + f * 4] = v;
        }
        __syncthreads();

        double acc[TB2];
#pragma unroll
        for (int i = 0; i < TB2; ++i) acc[i] = 0.0;

        const float4* wp = (const float4*)(w + (long)tid * HID + ks * SEGK);
        for (int kb = 0; kb < SEGK / 4; ++kb) {
            float4 wv = wp[kb];
            double w0 = wv.x, w1 = wv.y, w2 = wv.z, w3 = wv.w;
#pragma unroll
            for (int i = 0; i < TB2; ++i) {
                float4 xv = *(const float4*)&xls[i * SEGK + kb * 4];
                acc[i] = fma((double)xv.x, w0, acc[i]);
                acc[i] = fma((double)xv.y, w1, acc[i]);
                acc[i] = fma((double)xv.z, w2, acc[i]);
                acc[i] = fma((double)xv.w, w3, acc[i]);
            }
        }
#pragma unroll
        for (int i = 0; i < TB2; ++i) {
            long pofs = (((long)(s0 - base) + i) * KSEG + ks) * NEXP + tid;
            part[pofs] = acc[i];
        }
        __syncthreads();
    }
}

// ---------------------------------------------------------------------------
// Kernel 3: reduce partials + exact fp64 gating for flagged tokens
// ---------------------------------------------------------------------------
__global__ __launch_bounds__(256)
void repair_gate(const float* __restrict__ bias, const int* __restrict__ list,
                 const int* __restrict__ cntp, const double* __restrict__ part,
                 float* __restrict__ out, int base, int cap)
{
    __shared__ double lgl[TBG * NEXP];
    __shared__ int tokls[TBG];
    const int tid = threadIdx.x;

    int cnt = *cntp;
    if (cnt > 2 * cap)  cnt = 2 * cap;
    if (cnt > LISTCAP)  cnt = LISTCAP;
    const int cEnd = min(cnt, base + cap);

    float* out_idx = out;
    float* out_w   = out + (long)T_TOT * 8;

    const int l     = tid & 31;
    const int lane  = tid & 63;
    const int hbase = lane & 32;
    const int hw    = tid >> 5;
    const int myGLo = l >> 3;

    double bb[8];
    {
        float4 b0 = *(const float4*)&bias[4 * l];
        float4 b1 = *(const float4*)&bias[4 * l + 128];
        bb[0] = b0.x; bb[1] = b0.y; bb[2] = b0.z; bb[3] = b0.w;
        bb[4] = b1.x; bb[5] = b1.y; bb[6] = b1.z; bb[7] = b1.w;
    }

    for (int s0 = base + blockIdx.x * TBG; s0 < cEnd; s0 += gridDim.x * TBG) {
        if (tid < TBG) {
            int slot = s0 + tid;
            tokls[tid] = (slot < cEnd) ? list[slot] : 0;
        }
#pragma unroll
        for (int i = 0; i < TBG; ++i) {
            long pbase = (((long)(s0 - base) + i) * KSEG) * NEXP + tid;
            double s = 0.0;
#pragma unroll
            for (int ks = 0; ks < KSEG; ++ks) s += part[pbase + ks * NEXP];
            lgl[i * NEXP + tid] = s;
        }
        __syncthreads();
        {
            const int slot = s0 + hw;
            const bool valid = (slot < cEnd);
            const long t = tokls[hw];

            double sc[8], cs[8];
#pragma unroll
            for (int j = 0; j < 4; ++j) {
                double lg = lgl[hw * NEXP + 4 * l + j];
                sc[j] = 1.0 / (1.0 + exp(-lg));
                cs[j] = sc[j] + bb[j];
            }
#pragma unroll
            for (int j = 4; j < 8; ++j) {
                double lg = lgl[hw * NEXP + 128 + 4 * l + (j - 4)];
                sc[j] = 1.0 / (1.0 + exp(-lg));
                cs[j] = sc[j] + bb[j];
            }

            double l1, l2, h1, h2;
            {
                l1 = fmax(cs[0], cs[1]); l2 = fmin(cs[0], cs[1]);
                double n1 = fmax(l1, cs[2]); double n2 = fmax(fmin(l1, cs[2]), l2); l1 = n1; l2 = n2;
                n1 = fmax(l1, cs[3]); n2 = fmax(fmin(l1, cs[3]), l2); l1 = n1; l2 = n2;
                h1 = fmax(cs[4], cs[5]); h2 = fmin(cs[4], cs[5]);
                n1 = fmax(h1, cs[6]); n2 = fmax(fmin(h1, cs[6]), h2); h1 = n1; h2 = n2;
                n1 = fmax(h1, cs[7]); n2 = fmax(fmin(h1, cs[7]), h2); h1 = n1; h2 = n2;
            }
#pragma unroll
            for (int d = 1; d < 8; d <<= 1) {
                double o1 = __shfl_xor(l1, d), o2 = __shfl_xor(l2, d);
                double n1 = fmax(l1, o1);
                double n2 = fmax(fmin(l1, o1), fmax(l2, o2));
                l1 = n1; l2 = n2;
                o1 = __shfl_xor(h1, d); o2 = __shfl_xor(h2, d);
                n1 = fmax(h1, o1);
                n2 = fmax(fmin(h1, o1), fmax(h2, o2));
                h1 = n1; h2 = n2;
            }
            const double gLo = l1 + l2;
            const double gHi = h1 + h2;

            int rLo = 0, rHi = 0;
#pragma unroll
            for (int g = 0; g < 8; ++g) {
                double v = (g < 4) ? __shfl(gLo, hbase + g * 8)
                                   : __shfl(gHi, hbase + (g - 4) * 8);
                rLo += (v > gLo || (v == gLo && g < myGLo)) ? 1 : 0;
                rHi += (v > gHi || (v == gHi && g < myGLo + 4)) ? 1 : 0;
            }
            const bool selLo = (rLo < 4);
            const bool selHi = (rHi < 4);

            double mv[8];
#pragma unroll
            for (int j = 0; j < 8; ++j)
                mv[j] = ((j < 4) ? selLo : selHi) ? cs[j] : -INFINITY;

            double wsum = 0.0, my_w = 0.0;
            int my_ii = 0;
#pragma unroll
            for (int k = 0; k < 8; ++k) {
                double bv = mv[0]; int bj = 0;
                if (mv[1] > bv) { bv = mv[1]; bj = 1; }
                if (mv[2] > bv) { bv = mv[2]; bj = 2; }
                if (mv[3] > bv) { bv = mv[3]; bj = 3; }
                if (mv[4] > bv) { bv = mv[4]; bj = 4; }
                if (mv[5] > bv) { bv = mv[5]; bj = 5; }
                if (mv[6] > bv) { bv = mv[6]; bj = 6; }
                if (mv[7] > bv) { bv = mv[7]; bj = 7; }
                double v = bv;
                int ii = (bj < 4) ? (4 * l + bj) : (128 + 4 * l + (bj - 4));
#pragma unroll
                for (int d = 1; d < 32; d <<= 1) {
                    double ov = __shfl_xor(v, d);
                    int    oi = __shfl_xor(ii, d);
                    if (ov > v || (ov == v && oi < ii)) { v = ov; ii = oi; }
                }
                const int hi8 = ii >> 7;
                const int oj  = (ii & 3) + 4 * hi8;
                const int ol  = (ii & 127) >> 2;
                double ssel = (oj == 0) ? sc[0] : (oj == 1) ? sc[1] : (oj == 2) ? sc[2] :
                              (oj == 3) ? sc[3] : (oj == 4) ? sc[4] : (oj == 5) ? sc[5] :
                              (oj == 6) ? sc[6] : sc[7];
                double su = __shfl(ssel, hbase + ol);
                wsum += su;
                if (l == k) { my_ii = ii; my_w = su; }
#pragma unroll
                for (int j = 0; j < 8; ++j) {
                    int jj = (j < 4) ? (4 * l + j) : (128 + 4 * l + (j - 4));
                    if (jj == ii) mv[j] = -INFINITY;
                }
            }

            const double scale = 2.5 / (wsum + 1e-20);
            if (valid && l < 8) {
                out_idx[t * 8 + l] = (float)my_ii;
                out_w[t * 8 + l]   = (float)(my_w * scale);
            }
        }
        __syncthreads();
    }
}

// ---------------------------------------------------------------------------
extern "C" void kernel_launch(void* const* d_in, const int* in_sizes, int n_in,
                              void* d_out, int out_size, void* d_ws, size_t ws_size,
                              hipStream_t stream)
{
    const float* x    = (const float*)d_in[0];
    const float* w    = (const float*)d_in[1];
    const float* bias = (const float*)d_in[2];
    float* out = (float*)d_out;

    int*    cnt  = (int*)d_ws;                          // [0,256)
    int*    list = (int*)((char*)d_ws + 256);           // 64 KB
    bf16_t* whi  = (bf16_t*)((char*)d_ws + 66048);      // 3,670,016 B
    bf16_t* wlo  = (bf16_t*)((char*)d_ws + 66048 + 3670016);
    double* part = (double*)((char*)d_ws + 7406080);

    size_t avail = (ws_size > 7406080) ? (ws_size - 7406080) : 0;
    long cap_l = (long)(avail / ((size_t)KSEG * NEXP * 8));   // 32 KB per slot
    int CAP = (int)(cap_l > 4096 ? 4096 : cap_l);

    hipMemsetAsync(d_ws, 0, 4, stream);
    prep_w<<<896, 256, 0, stream>>>(w, whi, wlo);
    gate_mfma<<<256, 512, SMEM_SZ, stream>>>(x, whi, wlo, bias, out, cnt, list);
    if (CAP > 0) {
        for (int p = 0; p < 2; ++p) {
            repair_partial<<<dim3(32, KSEG), 256, 0, stream>>>(x, w, list, cnt, part, p * CAP, CAP);
            repair_gate<<<64, 256, 0, stream>>>(bias, list, cnt, part, out, p * CAP, CAP);
        }
    }
}